// Round 1
// baseline (196.700 us; speedup 1.0000x reference)
//
#include <hip/hip_runtime.h>
#include <hip/hip_cooperative_groups.h>
#include <math.h>

namespace cg = cooperative_groups;

#define BM 60      // modes per batch
#define TT 80      // timesteps
#define NAG 128    // agents
#define NLANES 64
#define NPTS 20
#define NLP (NLANES * NPTS)  // 1280 lane points
#define BIGOFF 1e8f

// Single cooperative launch: phase 1 = per-(b,m) rule scoring (one block of
// 4 waves per mode; wave w owns t in [20w, 20w+20)), grid.sync(), phase 2 =
// per-b softmax+argmax+trajectory copy on blocks bm < B (one wave each).
// Both rule checks are EXISTENCE queries -> chunk-of-64 scan with exact
// early exit on the first witness (branch on ballot = wave-uniform).
// Masks folded into x coordinate (+1e8): masked points can never satisfy
// d^2 < 4 nor d^2 <= 9 — identical booleans to the reference's +1e6 penalty.
__global__ __launch_bounds__(256) void fused_kernel(
    const float* __restrict__ logits,  // (B, M)
    const float* __restrict__ trajs,   // (B, M, T, 3)
    const float* __restrict__ agents,  // (B, NAG, 4)
    const float* __restrict__ amask,   // (B, NAG)
    const float* __restrict__ lanes,   // (B, NLANES, NPTS, 3)
    const float* __restrict__ lmask,   // (B, NLANES)
    float* __restrict__ scores,        // (B*M,) workspace
    float* __restrict__ out,           // traj (B*T*3) then idx (B)
    int B)
{
    __shared__ float s_px[NLP], s_py[NLP];   // lane points SoA (mask in x)
    __shared__ float s_ex[TT], s_ey[TT];
    __shared__ float s_lm[NLANES];
    __shared__ float s_j[2];
    __shared__ float s_cc[4], s_cd[4];

    const int bm   = blockIdx.x;   // b*M + m
    const int b    = bm / BM;
    const int tid  = threadIdx.x;  // 0..255
    const int w    = tid >> 6;     // wave 0..3
    const int lane = tid & 63;

    // ---- staging ----
    if (tid < NLANES) s_lm[tid] = (1.0f - lmask[b * NLANES + tid]) * BIGOFF;

    const float* tr = trajs + (size_t)bm * TT * 3;
    for (int i = tid; i < TT; i += 256) {
        s_ex[i] = tr[3 * i];
        s_ey[i] = tr[3 * i + 1];
    }
    // agents: 16-byte records -> 4 registers, mask folded into x
    float ax0, ay0, ax1, ay1;
    {
        const float4* ga4 = (const float4*)(agents + (size_t)b * NAG * 4);
        const float4 a0 = ga4[lane];
        const float4 a1 = ga4[64 + lane];
        ax0 = a0.x + (1.0f - amask[b * NAG + lane]) * BIGOFF;
        ay0 = a0.y;
        ax1 = a1.x + (1.0f - amask[b * NAG + 64 + lane]) * BIGOFF;
        ay1 = a1.y;
    }
    __syncthreads();  // s_lm ready (needed by the point-staging loop)

    const float* lbase = lanes + (size_t)b * NLP * 3;
    for (int p = tid; p < NLP; p += 256) {
        s_px[p] = lbase[3 * p] + s_lm[p / NPTS];
        s_py[p] = lbase[3 * p + 1];
    }
    __syncthreads();

    // comfort: jerk[t] = x[t+3]-3x[t+2]+3x[t+1]-x[t], t in [0,77)
    float jsum = 0.0f;
    if (tid < TT - 3) {
        const float jx = s_ex[tid + 3] - 3.0f * s_ex[tid + 2] + 3.0f * s_ex[tid + 1] - s_ex[tid];
        const float jy = s_ey[tid + 3] - 3.0f * s_ey[tid + 2] + 3.0f * s_ey[tid + 1] - s_ey[tid];
        jsum = sqrtf(jx * jx + jy * jy);
    }
    for (int off = 32; off > 0; off >>= 1) jsum += __shfl_xor(jsum, off, 64);
    if (w < 2 && lane == 0) s_j[w] = jsum;

    // ---- rule checks with exact early exit ----
    int ccoll = 0, cdriv = 0;
    const int t0 = w * (TT / 4);
    for (int t = t0; t < t0 + TT / 4; ++t) {
        const float ex = s_ex[t], ey = s_ey[t];  // broadcast reads

        // collision: exists agent with d^2 < 4 (2 register chunks)
        {
            float dx = ex - ax0, dy = ey - ay0;
            unsigned long long m = __ballot(fmaf(dx, dx, dy * dy) < 4.0f);
            if (m == 0ull) {
                dx = ex - ax1; dy = ey - ay1;
                m = __ballot(fmaf(dx, dx, dy * dy) < 4.0f);
            }
            ccoll += (m != 0ull) ? 1 : 0;
        }
        // drivable violation: NO lane point with d^2 <= 9 (20 LDS chunks)
        {
            unsigned long long m = 0ull;
            for (int k = 0; k < NLP / 64; ++k) {
                const int p = k * 64 + lane;
                const float dx = ex - s_px[p];
                const float dy = ey - s_py[p];
                m = __ballot(fmaf(dx, dx, dy * dy) <= 9.0f);
                if (m != 0ull) break;   // witness found: min <= 3, exact
            }
            cdriv += (m == 0ull) ? 1 : 0;
        }
    }
    if (lane == 0) { s_cc[w] = (float)ccoll; s_cd[w] = (float)cdriv; }
    __syncthreads();

    if (tid == 0) {
        const float coll = s_cc[0] + s_cc[1] + s_cc[2] + s_cc[3];
        const float driv = s_cd[0] + s_cd[1] + s_cd[2] + s_cd[3];
        const float comfort  = -((s_j[0] + s_j[1]) / (float)(TT - 3));
        const float progress = s_ex[TT - 1];
        scores[bm] = 0.1f * comfort + 0.5f * progress
                   - 1.0f * (coll / (float)TT)
                   - 0.3f * (driv / (float)TT);
    }

    // make scores visible device-wide before the grid barrier (per-XCD L2)
    __threadfence();
    cg::this_grid().sync();

    // ---- phase 2: per-b softmax over M=60 logits, add partial scores,
    // argmax (first-index tie-break like jnp.argmax), emit winner ----
    if (bm < B && tid < 64) {
        __threadfence();  // acquire: don't read stale scores through L1
        const int bb = bm;

        float lg = (tid < BM) ? logits[bb * BM + tid] : -1e30f;
        float mx = lg;
        for (int off = 32; off > 0; off >>= 1) mx = fmaxf(mx, __shfl_xor(mx, off, 64));
        float e = (tid < BM) ? expf(lg - mx) : 0.0f;
        float sum = e;
        for (int off = 32; off > 0; off >>= 1) sum += __shfl_xor(sum, off, 64);

        float sc = (tid < BM) ? (e / sum + scores[bb * BM + tid]) : -1e30f;
        int idx = tid;
        for (int off = 32; off > 0; off >>= 1) {
            float os = __shfl_xor(sc, off, 64);
            int   oi = __shfl_xor(idx, off, 64);
            if (os > sc || (os == sc && oi < idx)) { sc = os; idx = oi; }
        }
        // trajectory copy: 240 floats = 60 float4s, lanes 0..59
        const float4* src4 = (const float4*)(trajs + ((size_t)bb * BM + idx) * TT * 3);
        float4* dst4 = (float4*)(out + (size_t)bb * TT * 3);
        if (tid < (TT * 3) / 4) dst4[tid] = src4[tid];
        if (tid == 0) out[B * TT * 3 + bb] = (float)idx;
    }
}

extern "C" void kernel_launch(void* const* d_in, const int* in_sizes, int n_in,
                              void* d_out, int out_size, void* d_ws, size_t ws_size,
                              hipStream_t stream) {
    const float* logits = (const float*)d_in[0];
    const float* trajs  = (const float*)d_in[1];
    const float* agents = (const float*)d_in[2];
    const float* amask  = (const float*)d_in[3];
    const float* lanes  = (const float*)d_in[4];
    const float* lmask  = (const float*)d_in[5];

    int B = in_sizes[0] / BM;        // 16
    float* scores = (float*)d_ws;    // B*M floats of scratch
    float* out    = (float*)d_out;

    void* args[] = {(void*)&logits, (void*)&trajs, (void*)&agents, (void*)&amask,
                    (void*)&lanes, (void*)&lmask, (void*)&scores, (void*)&out, (void*)&B};
    hipLaunchCooperativeKernel((void*)fused_kernel, dim3(B * BM), dim3(256),
                               args, 0, stream);
}

// Round 2
// 98.963 us; speedup vs baseline: 1.9876x; 1.9876x over previous
//
#include <hip/hip_runtime.h>
#include <math.h>

#define BM 60      // modes per batch
#define TT 80      // timesteps
#define NAG 128    // agents
#define NLANES 64
#define NPTS 20
#define NLP (NLANES * NPTS)  // 1280 lane points
#define BIGOFF 1e8f

// Single standard launch. Phase 1: per-(b,m) rule scoring, one block of 4
// waves per mode (wave w owns t in [20w, 20w+20)). Completion: each block
// does a device-scope atomicAdd on cnt[b]; the 60th arriver for batch b runs
// phase 2 (softmax + argmax + winner copy) inline. No grid barrier.
//
// Workspace is POISONED with an unknown uniform dword pattern each iteration,
// so the arrival test is relative: P = poison dword read from an untouched ws
// word; last-arriver iff (old - P) % 60 == 59 (mod makes repeated replays
// without re-poison safe: each replay adds exactly 60 per b).
//
// Both rule checks are EXISTENCE queries -> chunk-of-64 scan with exact
// early exit on the first witness (branch on ballot = wave-uniform).
// Masks folded into x coordinate (+1e8): masked points can never satisfy
// d^2 < 4 nor d^2 <= 9 — identical booleans to the reference's +1e6 penalty.
__global__ __launch_bounds__(256) void fused_kernel(
    const float* __restrict__ logits,   // (B, M)
    const float* __restrict__ trajs,    // (B, M, T, 3)
    const float* __restrict__ agents,   // (B, NAG, 4)
    const float* __restrict__ amask,    // (B, NAG)
    const float* __restrict__ lanes,    // (B, NLANES, NPTS, 3)
    const float* __restrict__ lmask,    // (B, NLANES)
    float* __restrict__ scores,         // ws+0      : B*M floats
    unsigned* __restrict__ cnt,         // ws+8KB    : B counters
    const unsigned* __restrict__ probe, // ws+1MB    : untouched poison word
    float* __restrict__ out,            // traj (B*T*3) then idx (B)
    int B)
{
    __shared__ float s_px[NLP], s_py[NLP];   // lane points SoA (mask in x)
    __shared__ float s_ex[TT], s_ey[TT];
    __shared__ float s_lm[NLANES];
    __shared__ float s_j[2];
    __shared__ float s_cc[4], s_cd[4];
    __shared__ int   s_sel;

    const int bm   = blockIdx.x;   // b*M + m
    const int b    = bm / BM;
    const int tid  = threadIdx.x;  // 0..255
    const int w    = tid >> 6;     // wave 0..3
    const int lane = tid & 63;

    // poison baseline for the arrival counter (uniform fill pattern; this
    // word is never written by us). Read early to hide latency.
    unsigned P = 0;
    if (tid == 0)
        P = __hip_atomic_load(probe, __ATOMIC_RELAXED, __HIP_MEMORY_SCOPE_AGENT);

    // ---- staging ----
    if (tid < NLANES) s_lm[tid] = (1.0f - lmask[b * NLANES + tid]) * BIGOFF;

    const float* tr = trajs + (size_t)bm * TT * 3;
    for (int i = tid; i < TT; i += 256) {
        s_ex[i] = tr[3 * i];
        s_ey[i] = tr[3 * i + 1];
    }
    // agents: 16-byte records -> 4 registers, mask folded into x
    float ax0, ay0, ax1, ay1;
    {
        const float4* ga4 = (const float4*)(agents + (size_t)b * NAG * 4);
        const float4 a0 = ga4[lane];
        const float4 a1 = ga4[64 + lane];
        ax0 = a0.x + (1.0f - amask[b * NAG + lane]) * BIGOFF;
        ay0 = a0.y;
        ax1 = a1.x + (1.0f - amask[b * NAG + 64 + lane]) * BIGOFF;
        ay1 = a1.y;
    }
    __syncthreads();  // s_lm ready (needed by the point-staging loop)

    const float* lbase = lanes + (size_t)b * NLP * 3;
    for (int p = tid; p < NLP; p += 256) {
        s_px[p] = lbase[3 * p] + s_lm[p / NPTS];
        s_py[p] = lbase[3 * p + 1];
    }
    __syncthreads();

    // comfort: jerk[t] = x[t+3]-3x[t+2]+3x[t+1]-x[t], t in [0,77)
    float jsum = 0.0f;
    if (tid < TT - 3) {
        const float jx = s_ex[tid + 3] - 3.0f * s_ex[tid + 2] + 3.0f * s_ex[tid + 1] - s_ex[tid];
        const float jy = s_ey[tid + 3] - 3.0f * s_ey[tid + 2] + 3.0f * s_ey[tid + 1] - s_ey[tid];
        jsum = sqrtf(jx * jx + jy * jy);
    }
    for (int off = 32; off > 0; off >>= 1) jsum += __shfl_xor(jsum, off, 64);
    if (w < 2 && lane == 0) s_j[w] = jsum;

    // ---- rule checks with exact early exit ----
    int ccoll = 0, cdriv = 0;
    const int t0 = w * (TT / 4);
    for (int t = t0; t < t0 + TT / 4; ++t) {
        const float ex = s_ex[t], ey = s_ey[t];  // broadcast reads

        // collision: exists agent with d^2 < 4 (2 register chunks)
        {
            float dx = ex - ax0, dy = ey - ay0;
            unsigned long long m = __ballot(fmaf(dx, dx, dy * dy) < 4.0f);
            if (m == 0ull) {
                dx = ex - ax1; dy = ey - ay1;
                m = __ballot(fmaf(dx, dx, dy * dy) < 4.0f);
            }
            ccoll += (m != 0ull) ? 1 : 0;
        }
        // drivable violation: NO lane point with d^2 <= 9 (20 LDS chunks)
        {
            unsigned long long m = 0ull;
            for (int k = 0; k < NLP / 64; ++k) {
                const int p = k * 64 + lane;
                const float dx = ex - s_px[p];
                const float dy = ey - s_py[p];
                m = __ballot(fmaf(dx, dx, dy * dy) <= 9.0f);
                if (m != 0ull) break;   // witness found: min <= 3, exact
            }
            cdriv += (m == 0ull) ? 1 : 0;
        }
    }
    if (lane == 0) { s_cc[w] = (float)ccoll; s_cd[w] = (float)cdriv; }
    __syncthreads();

    if (tid == 0) {
        const float coll = s_cc[0] + s_cc[1] + s_cc[2] + s_cc[3];
        const float driv = s_cd[0] + s_cd[1] + s_cd[2] + s_cd[3];
        const float comfort  = -((s_j[0] + s_j[1]) / (float)(TT - 3));
        const float progress = s_ex[TT - 1];
        scores[bm] = 0.1f * comfort + 0.5f * progress
                   - 1.0f * (coll / (float)TT)
                   - 0.3f * (driv / (float)TT);

        // publish, then arrive. Last arriver for this b runs selection.
        __threadfence();  // release: score visible device-wide before arrival
        const unsigned old = __hip_atomic_fetch_add(
            &cnt[b], 1u, __ATOMIC_ACQ_REL, __HIP_MEMORY_SCOPE_AGENT);
        s_sel = ((old - P) % (unsigned)BM == (unsigned)(BM - 1)) ? 1 : 0;
    }
    __syncthreads();

    // ---- phase 2 (last arriver only): per-b softmax over M=60 logits,
    // add partial scores, argmax (first-index tie-break), emit winner ----
    if (s_sel && tid < 64) {
        __threadfence();  // acquire: invalidate caches before reading scores

        float lg = (tid < BM) ? logits[b * BM + tid] : -1e30f;
        float mx = lg;
        for (int off = 32; off > 0; off >>= 1) mx = fmaxf(mx, __shfl_xor(mx, off, 64));
        float e = (tid < BM) ? expf(lg - mx) : 0.0f;
        float sum = e;
        for (int off = 32; off > 0; off >>= 1) sum += __shfl_xor(sum, off, 64);

        float sc = -1e30f;
        if (tid < BM) {
            const float ps = __hip_atomic_load(&scores[b * BM + tid],
                                               __ATOMIC_RELAXED,
                                               __HIP_MEMORY_SCOPE_AGENT);
            sc = e / sum + ps;
        }
        int idx = tid;
        for (int off = 32; off > 0; off >>= 1) {
            float os = __shfl_xor(sc, off, 64);
            int   oi = __shfl_xor(idx, off, 64);
            if (os > sc || (os == sc && oi < idx)) { sc = os; idx = oi; }
        }
        // trajectory copy: 240 floats = 60 float4s, lanes 0..59
        const float4* src4 = (const float4*)(trajs + ((size_t)b * BM + idx) * TT * 3);
        float4* dst4 = (float4*)(out + (size_t)b * TT * 3);
        if (tid < (TT * 3) / 4) dst4[tid] = src4[tid];
        if (tid == 0) out[B * TT * 3 + b] = (float)idx;
    }
}

extern "C" void kernel_launch(void* const* d_in, const int* in_sizes, int n_in,
                              void* d_out, int out_size, void* d_ws, size_t ws_size,
                              hipStream_t stream) {
    const float* logits = (const float*)d_in[0];
    const float* trajs  = (const float*)d_in[1];
    const float* agents = (const float*)d_in[2];
    const float* amask  = (const float*)d_in[3];
    const float* lanes  = (const float*)d_in[4];
    const float* lmask  = (const float*)d_in[5];

    const int B = in_sizes[0] / BM;  // 16
    float*    scores = (float*)d_ws;                              // ws+0
    unsigned* cnt    = (unsigned*)((char*)d_ws + 8192);           // ws+8KB
    const unsigned* probe = (const unsigned*)((char*)d_ws + (1u << 20)); // ws+1MB
    float* out = (float*)d_out;

    fused_kernel<<<B * BM, 256, 0, stream>>>(logits, trajs, agents, amask,
                                             lanes, lmask, scores, cnt, probe,
                                             out, B);
}

// Round 3
// 70.053 us; speedup vs baseline: 2.8079x; 1.4127x over previous
//
#include <hip/hip_runtime.h>
#include <math.h>

#define BM 60      // modes per batch
#define TT 80      // timesteps
#define NAG 128    // agents
#define NLANES 64
#define NPTS 20
#define NLP (NLANES * NPTS)  // 1280 lane points
#define BIGOFF 1e8f

// Single standard launch. Phase 1: per-(b,m) rule scoring, one block of 4
// waves per mode (wave w owns t in [20w, 20w+20)). Completion: each block
// publishes its score with an agent-scope WRITE-THROUGH atomic store (goes
// straight to the coherence point; no buffer_wbl2), orders it with a bare
// s_waitcnt vmcnt(0), then does a RELAXED agent-scope atomicAdd on cnt[b].
// The 60th arriver for batch b runs phase 2 inline, reading the 60 scores
// as agent-scope atomic loads (bypass stale L1/L2). No __threadfence —
// round 2 showed the fence's L2 writeback/invalidate cost ~30 us across
// 960 blocks.
//
// Workspace is POISONED with an unknown uniform dword pattern each iteration,
// so the arrival test is relative: P = poison dword read from an untouched ws
// word; last-arriver iff (old - P) % 60 == 59 (mod makes repeated replays
// without re-poison safe: each replay adds exactly 60 per b).
//
// Both rule checks are EXISTENCE queries -> chunk-of-64 scan with exact
// early exit on the first witness (branch on ballot = wave-uniform).
// Masks folded into x coordinate (+1e8): masked points can never satisfy
// d^2 < 4 nor d^2 <= 9 — identical booleans to the reference's +1e6 penalty.
__global__ __launch_bounds__(256) void fused_kernel(
    const float* __restrict__ logits,   // (B, M)
    const float* __restrict__ trajs,    // (B, M, T, 3)
    const float* __restrict__ agents,   // (B, NAG, 4)
    const float* __restrict__ amask,    // (B, NAG)
    const float* __restrict__ lanes,    // (B, NLANES, NPTS, 3)
    const float* __restrict__ lmask,    // (B, NLANES)
    float* __restrict__ scores,         // ws+0      : B*M floats
    unsigned* __restrict__ cnt,         // ws+8KB    : B counters, stride 16
    const unsigned* __restrict__ probe, // ws+1MB    : untouched poison word
    float* __restrict__ out,            // traj (B*T*3) then idx (B)
    int B)
{
    __shared__ float s_px[NLP], s_py[NLP];   // lane points SoA (mask in x)
    __shared__ float s_ex[TT], s_ey[TT];
    __shared__ float s_lm[NLANES];
    __shared__ float s_j[2];
    __shared__ float s_cc[4], s_cd[4];
    __shared__ int   s_sel;

    const int bm   = blockIdx.x;   // b*M + m
    const int b    = bm / BM;
    const int tid  = threadIdx.x;  // 0..255
    const int w    = tid >> 6;     // wave 0..3
    const int lane = tid & 63;

    // poison baseline for the arrival counter (uniform fill pattern; this
    // word is never written by us). Read early to hide latency.
    unsigned P = 0;
    if (tid == 0)
        P = __hip_atomic_load(probe, __ATOMIC_RELAXED, __HIP_MEMORY_SCOPE_AGENT);

    // ---- staging ----
    if (tid < NLANES) s_lm[tid] = (1.0f - lmask[b * NLANES + tid]) * BIGOFF;

    const float* tr = trajs + (size_t)bm * TT * 3;
    for (int i = tid; i < TT; i += 256) {
        s_ex[i] = tr[3 * i];
        s_ey[i] = tr[3 * i + 1];
    }
    // agents: 16-byte records -> 4 registers, mask folded into x
    float ax0, ay0, ax1, ay1;
    {
        const float4* ga4 = (const float4*)(agents + (size_t)b * NAG * 4);
        const float4 a0 = ga4[lane];
        const float4 a1 = ga4[64 + lane];
        ax0 = a0.x + (1.0f - amask[b * NAG + lane]) * BIGOFF;
        ay0 = a0.y;
        ax1 = a1.x + (1.0f - amask[b * NAG + 64 + lane]) * BIGOFF;
        ay1 = a1.y;
    }
    __syncthreads();  // s_lm ready (needed by the point-staging loop)

    const float* lbase = lanes + (size_t)b * NLP * 3;
    for (int p = tid; p < NLP; p += 256) {
        s_px[p] = lbase[3 * p] + s_lm[p / NPTS];
        s_py[p] = lbase[3 * p + 1];
    }
    __syncthreads();

    // comfort: jerk[t] = x[t+3]-3x[t+2]+3x[t+1]-x[t], t in [0,77)
    float jsum = 0.0f;
    if (tid < TT - 3) {
        const float jx = s_ex[tid + 3] - 3.0f * s_ex[tid + 2] + 3.0f * s_ex[tid + 1] - s_ex[tid];
        const float jy = s_ey[tid + 3] - 3.0f * s_ey[tid + 2] + 3.0f * s_ey[tid + 1] - s_ey[tid];
        jsum = sqrtf(jx * jx + jy * jy);
    }
    for (int off = 32; off > 0; off >>= 1) jsum += __shfl_xor(jsum, off, 64);
    if (w < 2 && lane == 0) s_j[w] = jsum;

    // ---- rule checks with exact early exit ----
    int ccoll = 0, cdriv = 0;
    const int t0 = w * (TT / 4);
    for (int t = t0; t < t0 + TT / 4; ++t) {
        const float ex = s_ex[t], ey = s_ey[t];  // broadcast reads

        // collision: exists agent with d^2 < 4 (2 register chunks)
        {
            float dx = ex - ax0, dy = ey - ay0;
            unsigned long long m = __ballot(fmaf(dx, dx, dy * dy) < 4.0f);
            if (m == 0ull) {
                dx = ex - ax1; dy = ey - ay1;
                m = __ballot(fmaf(dx, dx, dy * dy) < 4.0f);
            }
            ccoll += (m != 0ull) ? 1 : 0;
        }
        // drivable violation: NO lane point with d^2 <= 9 (20 LDS chunks)
        {
            unsigned long long m = 0ull;
            for (int k = 0; k < NLP / 64; ++k) {
                const int p = k * 64 + lane;
                const float dx = ex - s_px[p];
                const float dy = ey - s_py[p];
                m = __ballot(fmaf(dx, dx, dy * dy) <= 9.0f);
                if (m != 0ull) break;   // witness found: min <= 3, exact
            }
            cdriv += (m == 0ull) ? 1 : 0;
        }
    }
    if (lane == 0) { s_cc[w] = (float)ccoll; s_cd[w] = (float)cdriv; }
    __syncthreads();

    if (tid == 0) {
        const float coll = s_cc[0] + s_cc[1] + s_cc[2] + s_cc[3];
        const float driv = s_cd[0] + s_cd[1] + s_cd[2] + s_cd[3];
        const float comfort  = -((s_j[0] + s_j[1]) / (float)(TT - 3));
        const float progress = s_ex[TT - 1];
        const float sc = 0.1f * comfort + 0.5f * progress
                       - 1.0f * (coll / (float)TT)
                       - 0.3f * (driv / (float)TT);

        // publish score WRITE-THROUGH to the coherence point (no L2 wb),
        // wait for its ack, then arrive with a relaxed agent-scope add.
        __hip_atomic_store(&scores[bm], sc, __ATOMIC_RELAXED,
                           __HIP_MEMORY_SCOPE_AGENT);
        asm volatile("s_waitcnt vmcnt(0)" ::: "memory");
        const unsigned old = __hip_atomic_fetch_add(
            &cnt[b * 16], 1u, __ATOMIC_RELAXED, __HIP_MEMORY_SCOPE_AGENT);
        s_sel = ((old - P) % (unsigned)BM == (unsigned)(BM - 1)) ? 1 : 0;
    }
    __syncthreads();

    // ---- phase 2 (last arriver only): per-b softmax over M=60 logits,
    // add partial scores, argmax (first-index tie-break), emit winner ----
    if (s_sel && tid < 64) {
        float lg = (tid < BM) ? logits[b * BM + tid] : -1e30f;
        float mx = lg;
        for (int off = 32; off > 0; off >>= 1) mx = fmaxf(mx, __shfl_xor(mx, off, 64));
        float e = (tid < BM) ? expf(lg - mx) : 0.0f;
        float sum = e;
        for (int off = 32; off > 0; off >>= 1) sum += __shfl_xor(sum, off, 64);

        float sc = -1e30f;
        if (tid < BM) {
            // agent-scope load: reads the coherence point, not stale L1/L2
            const float ps = __hip_atomic_load(&scores[b * BM + tid],
                                               __ATOMIC_RELAXED,
                                               __HIP_MEMORY_SCOPE_AGENT);
            sc = e / sum + ps;
        }
        int idx = tid;
        for (int off = 32; off > 0; off >>= 1) {
            float os = __shfl_xor(sc, off, 64);
            int   oi = __shfl_xor(idx, off, 64);
            if (os > sc || (os == sc && oi < idx)) { sc = os; idx = oi; }
        }
        // trajectory copy: 240 floats = 60 float4s, lanes 0..59
        const float4* src4 = (const float4*)(trajs + ((size_t)b * BM + idx) * TT * 3);
        float4* dst4 = (float4*)(out + (size_t)b * TT * 3);
        if (tid < (TT * 3) / 4) dst4[tid] = src4[tid];
        if (tid == 0) out[B * TT * 3 + b] = (float)idx;
    }
}

extern "C" void kernel_launch(void* const* d_in, const int* in_sizes, int n_in,
                              void* d_out, int out_size, void* d_ws, size_t ws_size,
                              hipStream_t stream) {
    const float* logits = (const float*)d_in[0];
    const float* trajs  = (const float*)d_in[1];
    const float* agents = (const float*)d_in[2];
    const float* amask  = (const float*)d_in[3];
    const float* lanes  = (const float*)d_in[4];
    const float* lmask  = (const float*)d_in[5];

    const int B = in_sizes[0] / BM;  // 16
    float*    scores = (float*)d_ws;                              // ws+0
    unsigned* cnt    = (unsigned*)((char*)d_ws + 8192);           // ws+8KB, stride 64B
    const unsigned* probe = (const unsigned*)((char*)d_ws + (1u << 20)); // ws+1MB
    float* out = (float*)d_out;

    fused_kernel<<<B * BM, 256, 0, stream>>>(logits, trajs, agents, amask,
                                             lanes, lmask, scores, cnt, probe,
                                             out, B);
}

// Round 4
// 69.764 us; speedup vs baseline: 2.8195x; 1.0041x over previous
//
#include <hip/hip_runtime.h>
#include <math.h>

#define BM 60      // modes per batch
#define TT 80      // timesteps
#define NAG 128    // agents
#define NLANES 64
#define NPTS 20
#define NLP (NLANES * NPTS)  // 1280 lane points
#define BIGOFF 1e8f

// Single launch, one block of 4 waves per (b,m); wave w owns t in [20w,20w+20).
// Key change vs round 3: NO LDS staging of the 1280 lane points. Both rule
// checks are EXISTENCE queries that (on this data) exit on their first
// 64-element chunk, so chunk 0 of agents AND chunk 0 of lane points live in
// registers (mask folded into x: +1e8 -> can never satisfy d^2<4 / d^2<=9,
// identical booleans to the reference's +1e6 penalty). The exact fallback
// for chunks k>=1 reads lane points straight from global (15 KB/batch,
// L2-resident, shared by 60 blocks) — same semantics for arbitrary data,
// just slower on a path that is ~never taken.
//
// Completion protocol (validated round 3): publish score with agent-scope
// write-through atomic store, bare s_waitcnt vmcnt(0), relaxed agent-scope
// atomicAdd on cnt[b]; 60th arriver runs softmax+argmax+copy inline.
// Workspace is POISONED with an unknown uniform dword pattern, so arrival
// is tested relative to probe word P: (old-P) % 60 == 59.
__global__ __launch_bounds__(256) void fused_kernel(
    const float* __restrict__ logits,   // (B, M)
    const float* __restrict__ trajs,    // (B, M, T, 3)
    const float* __restrict__ agents,   // (B, NAG, 4)
    const float* __restrict__ amask,    // (B, NAG)
    const float* __restrict__ lanes,    // (B, NLANES, NPTS, 3)
    const float* __restrict__ lmask,    // (B, NLANES)
    float* __restrict__ scores,         // ws+0      : B*M floats
    unsigned* __restrict__ cnt,         // ws+8KB    : B counters, stride 16
    const unsigned* __restrict__ probe, // ws+1MB    : untouched poison word
    float* __restrict__ out,            // traj (B*T*3) then idx (B)
    int B)
{
    __shared__ float s_ex[TT], s_ey[TT];
    __shared__ float s_lm[NLANES];
    __shared__ float s_j[2];
    __shared__ float s_cc[4], s_cd[4];
    __shared__ int   s_sel;

    const int bm   = blockIdx.x;   // b*M + m
    const int b    = bm / BM;
    const int tid  = threadIdx.x;  // 0..255
    const int w    = tid >> 6;     // wave 0..3
    const int lane = tid & 63;

    // poison baseline (uniform fill pattern; this word is never written)
    unsigned P = 0;
    if (tid == 0)
        P = __hip_atomic_load(probe, __ATOMIC_RELAXED, __HIP_MEMORY_SCOPE_AGENT);

    // ---- staging (all global loads issued up front) ----
    // trajectory: 240 floats = 60 float4, scattered to SoA in LDS
    const float* tr = trajs + (size_t)bm * TT * 3;
    if (tid < 60) {
        const float4 f = ((const float4*)tr)[tid];
        #pragma unroll
        for (int j = 0; j < 4; ++j) {
            const int q = 4 * tid + j;       // raw element index 0..239
            const int t = q / 3, c = q - 3 * t;
            const float v = (&f.x)[j];
            if (c == 0)      s_ex[t] = v;
            else if (c == 1) s_ey[t] = v;
        }
    }
    if (tid < NLANES) s_lm[tid] = (1.0f - lmask[b * NLANES + tid]) * BIGOFF;

    // agents: two 64-chunks in registers, mask folded into x
    float ax0, ay0, ax1, ay1;
    {
        const float4* ga4 = (const float4*)(agents + (size_t)b * NAG * 4);
        const float4 a0 = ga4[lane];
        const float4 a1 = ga4[64 + lane];
        ax0 = a0.x + (1.0f - amask[b * NAG + lane]) * BIGOFF;
        ay0 = a0.y;
        ax1 = a1.x + (1.0f - amask[b * NAG + 64 + lane]) * BIGOFF;
        ay1 = a1.y;
    }
    // lane points chunk 0 (p = lane) in registers, mask folded into x
    const float* lbase = lanes + (size_t)b * NLP * 3;
    float c0x, c0y;
    {
        c0x = lbase[3 * lane] + (1.0f - lmask[b * NLANES + lane / NPTS]) * BIGOFF;
        c0y = lbase[3 * lane + 1];
    }
    __syncthreads();

    // comfort: jerk[t] = x[t+3]-3x[t+2]+3x[t+1]-x[t], t in [0,77)
    float jsum = 0.0f;
    if (tid < TT - 3) {
        const float jx = s_ex[tid + 3] - 3.0f * s_ex[tid + 2] + 3.0f * s_ex[tid + 1] - s_ex[tid];
        const float jy = s_ey[tid + 3] - 3.0f * s_ey[tid + 2] + 3.0f * s_ey[tid + 1] - s_ey[tid];
        jsum = sqrtf(jx * jx + jy * jy);
    }
    for (int off = 32; off > 0; off >>= 1) jsum += __shfl_xor(jsum, off, 64);
    if (w < 2 && lane == 0) s_j[w] = jsum;

    // ---- rule checks: register chunk-0 fast path, exact rare fallback ----
    int ccoll = 0, cdriv = 0;
    const int t0 = w * (TT / 4);
    #pragma unroll 4
    for (int t = t0; t < t0 + TT / 4; ++t) {
        const float ex = s_ex[t], ey = s_ey[t];  // LDS broadcast reads

        // collision: exists agent with d^2 < 4 (2 register chunks)
        {
            float dx = ex - ax0, dy = ey - ay0;
            unsigned long long m = __ballot(fmaf(dx, dx, dy * dy) < 4.0f);
            if (m == 0ull) {
                dx = ex - ax1; dy = ey - ay1;
                m = __ballot(fmaf(dx, dx, dy * dy) < 4.0f);
            }
            ccoll += (m != 0ull) ? 1 : 0;
        }
        // drivable violation: NO lane point with d^2 <= 9
        {
            float dx = ex - c0x, dy = ey - c0y;
            unsigned long long m = __ballot(fmaf(dx, dx, dy * dy) <= 9.0f);
            if (m == 0ull) {
                // rare exact fallback: chunks 1..19 straight from global (L2)
                for (int k = 1; k < NLP / 64; ++k) {
                    const int p = k * 64 + lane;
                    const float lx = lbase[3 * p] + s_lm[p / NPTS];
                    const float ly = lbase[3 * p + 1];
                    const float ddx = ex - lx, ddy = ey - ly;
                    m = __ballot(fmaf(ddx, ddx, ddy * ddy) <= 9.0f);
                    if (m != 0ull) break;   // witness found: min <= 3, exact
                }
            }
            cdriv += (m == 0ull) ? 1 : 0;
        }
    }
    if (lane == 0) { s_cc[w] = (float)ccoll; s_cd[w] = (float)cdriv; }
    __syncthreads();

    if (tid == 0) {
        const float coll = s_cc[0] + s_cc[1] + s_cc[2] + s_cc[3];
        const float driv = s_cd[0] + s_cd[1] + s_cd[2] + s_cd[3];
        const float comfort  = -((s_j[0] + s_j[1]) / (float)(TT - 3));
        const float progress = s_ex[TT - 1];
        const float sc = 0.1f * comfort + 0.5f * progress
                       - 1.0f * (coll / (float)TT)
                       - 0.3f * (driv / (float)TT);

        // publish write-through to the coherence point (no L2 maintenance),
        // wait for the ack, then arrive with a relaxed agent-scope add.
        __hip_atomic_store(&scores[bm], sc, __ATOMIC_RELAXED,
                           __HIP_MEMORY_SCOPE_AGENT);
        asm volatile("s_waitcnt vmcnt(0)" ::: "memory");
        const unsigned old = __hip_atomic_fetch_add(
            &cnt[b * 16], 1u, __ATOMIC_RELAXED, __HIP_MEMORY_SCOPE_AGENT);
        s_sel = ((old - P) % (unsigned)BM == (unsigned)(BM - 1)) ? 1 : 0;
    }
    __syncthreads();

    // ---- phase 2 (last arriver only): per-b softmax over M=60 logits,
    // add partial scores, argmax (first-index tie-break), emit winner ----
    if (s_sel && tid < 64) {
        float lg = (tid < BM) ? logits[b * BM + tid] : -1e30f;
        float mx = lg;
        for (int off = 32; off > 0; off >>= 1) mx = fmaxf(mx, __shfl_xor(mx, off, 64));
        float e = (tid < BM) ? expf(lg - mx) : 0.0f;
        float sum = e;
        for (int off = 32; off > 0; off >>= 1) sum += __shfl_xor(sum, off, 64);

        float sc = -1e30f;
        if (tid < BM) {
            // agent-scope load: reads the coherence point, not stale L1/L2
            const float ps = __hip_atomic_load(&scores[b * BM + tid],
                                               __ATOMIC_RELAXED,
                                               __HIP_MEMORY_SCOPE_AGENT);
            sc = e / sum + ps;
        }
        int idx = tid;
        for (int off = 32; off > 0; off >>= 1) {
            float os = __shfl_xor(sc, off, 64);
            int   oi = __shfl_xor(idx, off, 64);
            if (os > sc || (os == sc && oi < idx)) { sc = os; idx = oi; }
        }
        // trajectory copy: 240 floats = 60 float4s, lanes 0..59
        const float4* src4 = (const float4*)(trajs + ((size_t)b * BM + idx) * TT * 3);
        float4* dst4 = (float4*)(out + (size_t)b * TT * 3);
        if (tid < (TT * 3) / 4) dst4[tid] = src4[tid];
        if (tid == 0) out[B * TT * 3 + b] = (float)idx;
    }
}

extern "C" void kernel_launch(void* const* d_in, const int* in_sizes, int n_in,
                              void* d_out, int out_size, void* d_ws, size_t ws_size,
                              hipStream_t stream) {
    const float* logits = (const float*)d_in[0];
    const float* trajs  = (const float*)d_in[1];
    const float* agents = (const float*)d_in[2];
    const float* amask  = (const float*)d_in[3];
    const float* lanes  = (const float*)d_in[4];
    const float* lmask  = (const float*)d_in[5];

    const int B = in_sizes[0] / BM;  // 16
    float*    scores = (float*)d_ws;                              // ws+0
    unsigned* cnt    = (unsigned*)((char*)d_ws + 8192);           // ws+8KB, stride 64B
    const unsigned* probe = (const unsigned*)((char*)d_ws + (1u << 20)); // ws+1MB
    float* out = (float*)d_out;

    fused_kernel<<<B * BM, 256, 0, stream>>>(logits, trajs, agents, amask,
                                             lanes, lmask, scores, cnt, probe,
                                             out, B);
}